// Round 1
// baseline (430.585 us; speedup 1.0000x reference)
//
#include <hip/hip_runtime.h>

// Problem constants (fixed by the reference)
#define S_LEN 2048
#define BATCH 2
#define KDIM  2048
#define NH    32
#define NKV   8
#define HDIM  64

typedef short bf16s;
typedef short bf16x8 __attribute__((ext_vector_type(8)));
typedef short bf16x4 __attribute__((ext_vector_type(4)));
typedef float f32x4  __attribute__((ext_vector_type(4)));

__device__ __forceinline__ bf16s f2bf(float f) {
  union { float f; unsigned u; } v; v.f = f;
  unsigned u = v.u;
  return (bf16s)((u + 0x7FFFu + ((u >> 16) & 1u)) >> 16);   // RNE
}
__device__ __forceinline__ float bf2f(bf16s b) {
  union { unsigned u; float f; } v;
  v.u = ((unsigned)(unsigned short)b) << 16;
  return v.f;
}

// async global -> LDS, 16B per lane, LDS dest = wave-uniform base + lane*16
__device__ __forceinline__ void gload16(const void* g, void* l) {
  __builtin_amdgcn_global_load_lds(
      (const __attribute__((address_space(1))) char*)g,
      (__attribute__((address_space(3))) char*)l, 16, 0, 0);
}

// ---------------- fp32 -> bf16 convert ----------------
__global__ void k_cvt(const float* __restrict__ src, bf16s* __restrict__ dst, int n) {
  int i = (blockIdx.x * blockDim.x + threadIdx.x) * 8;
  int stride = gridDim.x * blockDim.x * 8;
  for (; i < n; i += stride) {
    float4 a = *(const float4*)(src + i);
    float4 b = *(const float4*)(src + i + 4);
    bf16x8 o;
    o[0]=f2bf(a.x); o[1]=f2bf(a.y); o[2]=f2bf(a.z); o[3]=f2bf(a.w);
    o[4]=f2bf(b.x); o[5]=f2bf(b.y); o[6]=f2bf(b.z); o[7]=f2bf(b.w);
    *(bf16x8*)(dst + i) = o;
  }
}

// ---------------- GEMM: C[m][n] = sum_k A[m][k] * Bw[n][k] ----------------
// m97 structure: 128x128 tile, BK=32, 4 waves (each 64x64), global_load_lds(16B),
// linear LDS, ds_read_b128 fragments, 16 MFMA per K-step.
// EPI: 0 = bf16 row-major (ldc=N); 1 = V^T per-(b,kv_head) [d][s]; 2 = fp32 row-major
template<int EPI>
__global__ __launch_bounds__(256, 2)
void k_gemm_bt(const bf16s* __restrict__ A, const bf16s* __restrict__ Bw,
               void* __restrict__ Cout, int M, int N, int K) {
  __shared__ bf16s As[128 * 32];
  __shared__ bf16s Bs[128 * 32];
  const int tid  = threadIdx.x;
  const int lane = tid & 63;
  const int w    = tid >> 6;
  const int wr   = w >> 1, wc = w & 1;
  const int l15  = lane & 15, lg = lane >> 4;
  const int by = blockIdx.y, bx = blockIdx.x;

  f32x4 acc[4][4] = {};

  // staging granules: g0 = tid (rows 0..63), g1 = tid+256 (rows 64..127)
  const bf16s* gA0 = A  + (size_t)(by * 128 + (tid >> 2)) * K + ((tid & 3) << 3);
  const bf16s* gA1 = gA0 + (size_t)64 * K;
  const bf16s* gB0 = Bw + (size_t)(bx * 128 + (tid >> 2)) * K + ((tid & 3) << 3);
  const bf16s* gB1 = gB0 + (size_t)64 * K;
  bf16s* lA0 = &As[w * 512];        // wave-uniform LDS bases (lane*16 added by HW)
  bf16s* lA1 = &As[2048 + w * 512];
  bf16s* lB0 = &Bs[w * 512];
  bf16s* lB1 = &Bs[2048 + w * 512];

  const int nkt = K >> 5;
  for (int kt = 0; kt < nkt; ++kt) {
    __syncthreads();                      // previous compute done before overwrite
    const int ko = kt << 5;
    gload16(gA0 + ko, lA0);
    gload16(gA1 + ko, lA1);
    gload16(gB0 + ko, lB0);
    gload16(gB1 + ko, lB1);
    __syncthreads();                      // compiler drains vmcnt(0) before barrier

    const bf16s* pa = &As[(wr * 64 + l15) * 32 + lg * 8];
    const bf16s* pb = &Bs[(wc * 64 + l15) * 32 + lg * 8];
    bf16x8 a0 = *(const bf16x8*)(pa);
    bf16x8 a1 = *(const bf16x8*)(pa + 512);
    bf16x8 a2 = *(const bf16x8*)(pa + 1024);
    bf16x8 a3 = *(const bf16x8*)(pa + 1536);
    bf16x8 b0 = *(const bf16x8*)(pb);
    bf16x8 b1 = *(const bf16x8*)(pb + 512);
    bf16x8 b2 = *(const bf16x8*)(pb + 1024);
    bf16x8 b3 = *(const bf16x8*)(pb + 1536);
    bf16x8 av[4] = {a0, a1, a2, a3};
    bf16x8 bv[4] = {b0, b1, b2, b3};
#pragma unroll
    for (int mi = 0; mi < 4; ++mi)
#pragma unroll
      for (int ni = 0; ni < 4; ++ni)
        acc[mi][ni] = __builtin_amdgcn_mfma_f32_16x16x32_bf16(av[mi], bv[ni], acc[mi][ni], 0, 0, 0);
  }

  // epilogue: C row = by*128 + wr*64 + mi*16 + 4*lg + r ; col = bx*128 + wc*64 + ni*16 + l15
#pragma unroll
  for (int mi = 0; mi < 4; ++mi) {
    const int m0 = by * 128 + wr * 64 + mi * 16 + 4 * lg;
#pragma unroll
    for (int ni = 0; ni < 4; ++ni) {
      const int n = bx * 128 + wc * 64 + ni * 16 + l15;
      if (EPI == 0) {
        bf16s* C = (bf16s*)Cout;
        for (int r = 0; r < 4; ++r)
          C[(size_t)(m0 + r) * N + n] = f2bf(acc[mi][ni][r]);
      } else if (EPI == 2) {
        float* C = (float*)Cout;
        for (int r = 0; r < 4; ++r)
          C[(size_t)(m0 + r) * N + n] = acc[mi][ni][r];
      } else {
        // V^T: vt[((b*NKV + kvh)*HDIM + d) * S + s], 4 consecutive s per lane
        bf16s* C = (bf16s*)Cout;
        const int kvh = n >> 6, d = n & 63;
        const int b = m0 >> 11, s = m0 & (S_LEN - 1);
        bf16x4 pk;
        for (int r = 0; r < 4; ++r) pk[r] = f2bf(acc[mi][ni][r]);
        *(bf16x4*)&C[((size_t)((b * NKV + kvh) * HDIM + d)) * S_LEN + s] = pk;
      }
    }
  }
}

// ---------------- RoPE (in place, bf16) ----------------
__global__ void k_rope(bf16s* __restrict__ x, const int* __restrict__ pos, int cols) {
  const int row = blockIdx.y;
  const int c = blockIdx.x * blockDim.x + threadIdx.x;     // pair index within row
  const int i = c & 31;                                    // pair idx within head (HD/2=32)
  const int col0 = ((c >> 5) << 6) + 2 * i;                // h*64 + 2i
  const int p = pos[row];
  const float inv = expf(-(float)(2 * i) * (1.0f / 64.0f) * 9.210340371976184f); // ln(1e4)
  const float fr = (float)p * inv;
  const float sn = sinf(fr), cs = cosf(fr);
  bf16s* pp = x + (size_t)row * cols + col0;
  const float x1 = bf2f(pp[0]), x2 = bf2f(pp[1]);
  pp[0] = f2bf(x1 * cs - x2 * sn);
  pp[1] = f2bf(x2 * cs + x1 * sn);
}

// ---------------- Flash attention (causal GQA) ----------------
// grid (S/64, B*H); 4 waves x 16 q-rows; KV tiles of 64; 16x16x32 bf16 MFMA.
__global__ __launch_bounds__(256, 2)
void k_flash(const bf16s* __restrict__ q, const bf16s* __restrict__ k,
             const bf16s* __restrict__ vt, const int* __restrict__ amask,
             bf16s* __restrict__ out) {
  __shared__ bf16s Ks[64 * 64];   // [key][d], XOR-swizzled
  __shared__ bf16s Vs[64 * 64];   // [d][key] (V^T), XOR-swizzled
  __shared__ bf16s Ps[4 * 16 * 64]; // per-wave P, [qrow][key], XOR-swizzled

  const int tid = threadIdx.x, lane = tid & 63, w = tid >> 6;
  const int l15 = lane & 15, lg = lane >> 4;
  const int bx = blockIdx.x;
  const int bh = blockIdx.y;
  const int b = bh >> 5, h = bh & 31, kvh = h >> 2;

  // Q fragments (A-operand): row = l15, k = lg*8 (+32 for second half)
  const size_t qrow = (size_t)(b * S_LEN + bx * 64 + w * 16 + l15);
  const bf16x8 aq0 = *(const bf16x8*)(q + qrow * KDIM + h * HDIM + lg * 8);
  const bf16x8 aq1 = *(const bf16x8*)(q + qrow * KDIM + h * HDIM + 32 + lg * 8);

  float m_run[4], l_run[4];
  f32x4 ao[4] = {};
#pragma unroll
  for (int r = 0; r < 4; ++r) { m_run[r] = -1e30f; l_run[r] = 0.f; }

  const int qg0 = bx * 64 + w * 16 + 4 * lg;   // + r
  const bf16s* kbase = k + (size_t)b * S_LEN * (NKV * HDIM) + kvh * HDIM;
  const bf16s* vbase = vt + ((size_t)(b * NKV + kvh) * HDIM) * S_LEN;

  for (int kt = 0; kt <= bx; ++kt) {
    __syncthreads();
    // stage K tile [64 keys][64 d] and V^T tile [64 d][64 keys]
#pragma unroll
    for (int c = 0; c < 2; ++c) {
      const int g = tid + c * 256;
      const int row = g >> 3, off = (g & 7) * 8;
      const int sw = off ^ ((row & 7) << 3);
      bf16x8 kv = *(const bf16x8*)(kbase + (size_t)(kt * 64 + row) * (NKV * HDIM) + off);
      *(bf16x8*)&Ks[row * 64 + sw] = kv;
      bf16x8 vv = *(const bf16x8*)(vbase + (size_t)row * S_LEN + kt * 64 + off);
      *(bf16x8*)&Vs[row * 64 + sw] = vv;
    }
    __syncthreads();

    // scores: Q(16x64) @ K^T -> 4 chunks of 16x16
    f32x4 sc[4] = {};
#pragma unroll
    for (int nc = 0; nc < 4; ++nc) {
      const int krow = nc * 16 + l15;
      const bf16s* kp = &Ks[krow * 64];
      const int x = (krow & 7) << 3;
      bf16x8 kb0 = *(const bf16x8*)(kp + ((lg * 8) ^ x));
      bf16x8 kb1 = *(const bf16x8*)(kp + ((32 + lg * 8) ^ x));
      sc[nc] = __builtin_amdgcn_mfma_f32_16x16x32_bf16(aq0, kb0, sc[nc], 0, 0, 0);
      sc[nc] = __builtin_amdgcn_mfma_f32_16x16x32_bf16(aq1, kb1, sc[nc], 0, 0, 0);
    }

    // scale + mask + tile row-max
    float mt[4] = {-1e30f, -1e30f, -1e30f, -1e30f};
#pragma unroll
    for (int nc = 0; nc < 4; ++nc) {
      const int kg = kt * 64 + nc * 16 + l15;
      const bool mok = (amask[b * S_LEN + kg] != 0);
#pragma unroll
      for (int r = 0; r < 4; ++r) {
        float s = sc[nc][r] * 0.125f;
        if (kg > qg0 + r || !mok) s = -1e30f;
        sc[nc][r] = s;
        mt[r] = fmaxf(mt[r], s);
      }
    }
#pragma unroll
    for (int r = 0; r < 4; ++r) {
      float v = mt[r];
      v = fmaxf(v, __shfl_xor(v, 1));
      v = fmaxf(v, __shfl_xor(v, 2));
      v = fmaxf(v, __shfl_xor(v, 4));
      v = fmaxf(v, __shfl_xor(v, 8));
      mt[r] = v;
    }
    float alpha[4], mnew[4], rs[4] = {0, 0, 0, 0};
#pragma unroll
    for (int r = 0; r < 4; ++r) {
      mnew[r] = fmaxf(m_run[r], mt[r]);
      alpha[r] = __expf(m_run[r] - mnew[r]);
    }
#pragma unroll
    for (int nc = 0; nc < 4; ++nc)
#pragma unroll
      for (int r = 0; r < 4; ++r) {
        const float p = __expf(sc[nc][r] - mnew[r]);
        sc[nc][r] = p;
        rs[r] += p;
      }
#pragma unroll
    for (int r = 0; r < 4; ++r) {
      float v = rs[r];
      v += __shfl_xor(v, 1);
      v += __shfl_xor(v, 2);
      v += __shfl_xor(v, 4);
      v += __shfl_xor(v, 8);
      l_run[r] = l_run[r] * alpha[r] + v;
      m_run[r] = mnew[r];
    }
#pragma unroll
    for (int vc = 0; vc < 4; ++vc)
#pragma unroll
      for (int r = 0; r < 4; ++r) ao[vc][r] *= alpha[r];

    // P (C-layout) -> LDS -> A-fragment layout (wave-local)
#pragma unroll
    for (int nc = 0; nc < 4; ++nc)
#pragma unroll
      for (int r = 0; r < 4; ++r) {
        const int rr = 4 * lg + r;
        const int e = (nc * 16 + l15) ^ ((rr & 7) << 3);
        Ps[w * 1024 + rr * 64 + e] = f2bf(sc[nc][r]);
      }
    const bf16s* pp = &Ps[w * 1024 + l15 * 64];
    const int px = (l15 & 7) << 3;
    bf16x8 pa0 = *(const bf16x8*)(pp + ((lg * 8) ^ px));
    bf16x8 pa1 = *(const bf16x8*)(pp + ((32 + lg * 8) ^ px));

    // PV: P(16x64keys) @ V(64keys x 64d)
#pragma unroll
    for (int vc = 0; vc < 4; ++vc) {
      const int vrow = vc * 16 + l15;
      const bf16s* vp = &Vs[vrow * 64];
      const int x = (vrow & 7) << 3;
      bf16x8 vb0 = *(const bf16x8*)(vp + ((lg * 8) ^ x));
      bf16x8 vb1 = *(const bf16x8*)(vp + ((32 + lg * 8) ^ x));
      ao[vc] = __builtin_amdgcn_mfma_f32_16x16x32_bf16(pa0, vb0, ao[vc], 0, 0, 0);
      ao[vc] = __builtin_amdgcn_mfma_f32_16x16x32_bf16(pa1, vb1, ao[vc], 0, 0, 0);
    }
  }

  // normalize + store: out[(b*S + qrow)*KDIM + h*64 + d]
#pragma unroll
  for (int vc = 0; vc < 4; ++vc)
#pragma unroll
    for (int r = 0; r < 4; ++r) {
      const size_t m = (size_t)b * S_LEN + bx * 64 + w * 16 + 4 * lg + r;
      out[m * KDIM + h * HDIM + vc * 16 + l15] = f2bf(ao[vc][r] / l_run[r]);
    }
}

// ---------------- launch ----------------
extern "C" void kernel_launch(void* const* d_in, const int* in_sizes, int n_in,
                              void* d_out, int out_size, void* d_ws, size_t ws_size,
                              hipStream_t stream) {
  const float* x  = (const float*)d_in[0];
  const int* pos  = (const int*)d_in[1];
  const int* am   = (const int*)d_in[2];
  const float* Wq = (const float*)d_in[3];
  const float* Wk = (const float*)d_in[4];
  const float* Wv = (const float*)d_in[5];
  const float* Wo = (const float*)d_in[6];
  float* out = (float*)d_out;

  char* ws = (char*)d_ws;
  const int M = BATCH * S_LEN;                 // 4096
  bf16s* xb  = (bf16s*)(ws);                   // 4096x2048
  bf16s* wqb = (bf16s*)(ws + 16777216);        // 2048x2048
  bf16s* wkb = (bf16s*)(ws + 25165824);        // 512x2048
  bf16s* wvb = (bf16s*)(ws + 27262976);        // 512x2048
  bf16s* wob = (bf16s*)(ws + 29360128);        // 2048x2048
  bf16s* qb  = (bf16s*)(ws + 37748736);        // 4096x2048
  bf16s* kb  = (bf16s*)(ws + 54525952);        // 4096x512
  bf16s* vtb = (bf16s*)(ws + 58720256);        // (2*8*64)x2048  (V^T)
  bf16s* aob = (bf16s*)(ws + 62914560);        // 4096x2048

  dim3 blk(256);
  auto cvt = [&](const float* s, bf16s* d, int n) {
    int g = (n / 8 + 255) / 256; if (g > 2048) g = 2048;
    k_cvt<<<dim3(g), blk, 0, stream>>>(s, d, n);
  };
  cvt(x,  xb,  M * KDIM);
  cvt(Wq, wqb, 2048 * 2048);
  cvt(Wk, wkb, 512 * 2048);
  cvt(Wv, wvb, 512 * 2048);
  cvt(Wo, wob, 2048 * 2048);

  k_gemm_bt<0><<<dim3(16, 32), blk, 0, stream>>>(xb, wqb, qb, M, 2048, 2048);
  k_gemm_bt<0><<<dim3(4, 32),  blk, 0, stream>>>(xb, wkb, kb, M, 512, 2048);
  k_gemm_bt<1><<<dim3(4, 32),  blk, 0, stream>>>(xb, wvb, vtb, M, 512, 2048);

  k_rope<<<dim3(4, M), blk, 0, stream>>>(qb, pos, 2048);
  k_rope<<<dim3(1, M), blk, 0, stream>>>(kb, pos, 512);

  k_flash<<<dim3(S_LEN / 64, BATCH * NH), blk, 0, stream>>>(qb, kb, vtb, am, aob);

  k_gemm_bt<2><<<dim3(16, 32), blk, 0, stream>>>(aob, wob, out, M, 2048, 2048);
}

// Round 2
// 300.959 us; speedup vs baseline: 1.4307x; 1.4307x over previous
//
#include <hip/hip_runtime.h>

// Problem constants (fixed by the reference)
#define S_LEN 2048
#define BATCH 2
#define KDIM  2048
#define NH    32
#define NKV   8
#define HDIM  64

typedef short bf16s;
typedef short bf16x8 __attribute__((ext_vector_type(8)));
typedef short bf16x4 __attribute__((ext_vector_type(4)));
typedef float f32x4  __attribute__((ext_vector_type(4)));

__device__ __forceinline__ bf16s f2bf(float f) {
  union { float f; unsigned u; } v; v.f = f;
  unsigned u = v.u;
  return (bf16s)((u + 0x7FFFu + ((u >> 16) & 1u)) >> 16);   // RNE
}
__device__ __forceinline__ float bf2f(bf16s b) {
  union { unsigned u; float f; } v;
  v.u = ((unsigned)(unsigned short)b) << 16;
  return v.f;
}

// async global -> LDS, 16B per lane, LDS dest = wave-uniform base + lane*16
__device__ __forceinline__ void gload16(const void* g, void* l) {
  __builtin_amdgcn_global_load_lds(
      (const __attribute__((address_space(1))) char*)g,
      (__attribute__((address_space(3))) char*)l, 16, 0, 0);
}

// ---------------- fp32 -> bf16 convert ----------------
__global__ void k_cvt(const float* __restrict__ src, bf16s* __restrict__ dst, int n) {
  int i = (blockIdx.x * blockDim.x + threadIdx.x) * 8;
  int stride = gridDim.x * blockDim.x * 8;
  for (; i < n; i += stride) {
    float4 a = *(const float4*)(src + i);
    float4 b = *(const float4*)(src + i + 4);
    bf16x8 o;
    o[0]=f2bf(a.x); o[1]=f2bf(a.y); o[2]=f2bf(a.z); o[3]=f2bf(a.w);
    o[4]=f2bf(b.x); o[5]=f2bf(b.y); o[6]=f2bf(b.z); o[7]=f2bf(b.w);
    *(bf16x8*)(dst + i) = o;
  }
}

// ---------------- GEMM: C[m][n] = sum_k A[m][k] * Bw[n][k] ----------------
// EPI: 0 = bf16 row-major (ldc=N); 1 = V^T per-(b,kv_head) [d][s]; 2 = fp32 row-major
template<int EPI>
__global__ __launch_bounds__(256, 2)
void k_gemm_bt(const bf16s* __restrict__ A, const bf16s* __restrict__ Bw,
               void* __restrict__ Cout, int M, int N, int K) {
  __shared__ bf16s As[128 * 32];
  __shared__ bf16s Bs[128 * 32];
  const int tid  = threadIdx.x;
  const int lane = tid & 63;
  const int w    = tid >> 6;
  const int wr   = w >> 1, wc = w & 1;
  const int l15  = lane & 15, lg = lane >> 4;
  const int by = blockIdx.y, bx = blockIdx.x;

  f32x4 acc[4][4] = {};

  const bf16s* gA0 = A  + (size_t)(by * 128 + (tid >> 2)) * K + ((tid & 3) << 3);
  const bf16s* gA1 = gA0 + (size_t)64 * K;
  const bf16s* gB0 = Bw + (size_t)(bx * 128 + (tid >> 2)) * K + ((tid & 3) << 3);
  const bf16s* gB1 = gB0 + (size_t)64 * K;
  bf16s* lA0 = &As[w * 512];
  bf16s* lA1 = &As[2048 + w * 512];
  bf16s* lB0 = &Bs[w * 512];
  bf16s* lB1 = &Bs[2048 + w * 512];

  const int nkt = K >> 5;
  for (int kt = 0; kt < nkt; ++kt) {
    __syncthreads();
    const int ko = kt << 5;
    gload16(gA0 + ko, lA0);
    gload16(gA1 + ko, lA1);
    gload16(gB0 + ko, lB0);
    gload16(gB1 + ko, lB1);
    __syncthreads();

    const bf16s* pa = &As[(wr * 64 + l15) * 32 + lg * 8];
    const bf16s* pb = &Bs[(wc * 64 + l15) * 32 + lg * 8];
    bf16x8 a0 = *(const bf16x8*)(pa);
    bf16x8 a1 = *(const bf16x8*)(pa + 512);
    bf16x8 a2 = *(const bf16x8*)(pa + 1024);
    bf16x8 a3 = *(const bf16x8*)(pa + 1536);
    bf16x8 b0 = *(const bf16x8*)(pb);
    bf16x8 b1 = *(const bf16x8*)(pb + 512);
    bf16x8 b2 = *(const bf16x8*)(pb + 1024);
    bf16x8 b3 = *(const bf16x8*)(pb + 1536);
    bf16x8 av[4] = {a0, a1, a2, a3};
    bf16x8 bv[4] = {b0, b1, b2, b3};
#pragma unroll
    for (int mi = 0; mi < 4; ++mi)
#pragma unroll
      for (int ni = 0; ni < 4; ++ni)
        acc[mi][ni] = __builtin_amdgcn_mfma_f32_16x16x32_bf16(av[mi], bv[ni], acc[mi][ni], 0, 0, 0);
  }

#pragma unroll
  for (int mi = 0; mi < 4; ++mi) {
    const int m0 = by * 128 + wr * 64 + mi * 16 + 4 * lg;
#pragma unroll
    for (int ni = 0; ni < 4; ++ni) {
      const int n = bx * 128 + wc * 64 + ni * 16 + l15;
      if (EPI == 0) {
        bf16s* C = (bf16s*)Cout;
        for (int r = 0; r < 4; ++r)
          C[(size_t)(m0 + r) * N + n] = f2bf(acc[mi][ni][r]);
      } else if (EPI == 2) {
        float* C = (float*)Cout;
        for (int r = 0; r < 4; ++r)
          C[(size_t)(m0 + r) * N + n] = acc[mi][ni][r];
      } else {
        bf16s* C = (bf16s*)Cout;
        const int kvh = n >> 6, d = n & 63;
        const int b = m0 >> 11, s = m0 & (S_LEN - 1);
        bf16x4 pk;
        for (int r = 0; r < 4; ++r) pk[r] = f2bf(acc[mi][ni][r]);
        *(bf16x4*)&C[((size_t)((b * NKV + kvh) * HDIM + d)) * S_LEN + s] = pk;
      }
    }
  }
}

// ---------------- RoPE (in place, bf16, vectorized 8-wide) ----------------
__global__ void k_rope(bf16s* __restrict__ x, const int* __restrict__ pos, int cols) {
  const int row = blockIdx.y;
  const int c = blockIdx.x * blockDim.x + threadIdx.x;     // 8-elem chunk
  if (c * 8 >= cols) return;
  const int p = pos[row];
  const int i0 = ((c * 8) & 63) >> 1;                      // first pair idx in head
  bf16x8 v = *(bf16x8*)(x + (size_t)row * cols + c * 8);
  bf16x8 o;
#pragma unroll
  for (int j = 0; j < 4; ++j) {
    const int i = i0 + j;
    const float inv = expf(-(float)(2 * i) * (1.0f / 64.0f) * 9.210340371976184f);
    const float fr = (float)p * inv;
    const float sn = sinf(fr), cs = cosf(fr);
    const float x1 = bf2f(v[2 * j]), x2 = bf2f(v[2 * j + 1]);
    o[2 * j]     = f2bf(x1 * cs - x2 * sn);
    o[2 * j + 1] = f2bf(x2 * cs + x1 * sn);
  }
  *(bf16x8*)(x + (size_t)row * cols + c * 8) = o;
}

// ---------------- Flash attention (causal GQA), swapped-MFMA ----------------
// grid (B*H, S/128) heavy-first; 4 waves x 32 q-rows; KV tiles of 64, dbuf.
__global__ __launch_bounds__(256, 3)
void k_flash(const bf16s* __restrict__ q, const bf16s* __restrict__ k,
             const bf16s* __restrict__ vt, const int* __restrict__ amask,
             bf16s* __restrict__ out) {
  __shared__ bf16s Ks[2][64 * 64];   // [key][d], XOR-swizzled content, linear dest
  __shared__ bf16s Vs[2][64 * 64];   // [d][key] (V^T), XOR-swizzled
  __shared__ bf16s Ps[4][32 * 64];   // per-wave P[q'][key], XOR-swizzled

  const int tid = threadIdx.x, lane = tid & 63, w = tid >> 6;
  const int l15 = lane & 15, lg = lane >> 4;
  const int bh = blockIdx.x;
  const int qt = (S_LEN / 128 - 1) - blockIdx.y;           // heavy-first
  const int b = bh >> 5, h = bh & 31, kvh = h >> 2;
  const int nt = 2 * qt + 2;

  // Q fragments (B-operand): lane holds Q[qrow = l15][d = s*32 + lg*8 + j]
  bf16x8 aq[2][2];
  const int qbase = qt * 128 + w * 32;
#pragma unroll
  for (int u = 0; u < 2; ++u) {
    const size_t qr = (size_t)(b * S_LEN + qbase + u * 16 + l15);
#pragma unroll
    for (int s = 0; s < 2; ++s)
      aq[u][s] = *(const bf16x8*)(q + qr * KDIM + h * HDIM + s * 32 + lg * 8);
  }

  const bf16s* kbase = k + (size_t)b * S_LEN * (NKV * HDIM) + kvh * HDIM;
  const bf16s* vbase = vt + ((size_t)(b * NKV + kvh) * HDIM) * S_LEN;

  // staging: LDS linear byte = w*2048 + j*1024 + lane*16 -> row, col16 = (lane&7)^(row&7)
  const int srow0 = w * 16 + (lane >> 3);
  const int scol0 = (lane & 7) ^ (srow0 & 7);
  const int srow1 = srow0 + 8;
  const int scol1 = (lane & 7) ^ (srow1 & 7);

  auto stage = [&](int kt, int bufi) {
    gload16(kbase + (size_t)(kt * 64 + srow0) * (NKV * HDIM) + scol0 * 8, &Ks[bufi][w * 1024]);
    gload16(kbase + (size_t)(kt * 64 + srow1) * (NKV * HDIM) + scol1 * 8, &Ks[bufi][w * 1024 + 512]);
    gload16(vbase + (size_t)srow0 * S_LEN + kt * 64 + scol0 * 8, &Vs[bufi][w * 1024]);
    gload16(vbase + (size_t)srow1 * S_LEN + kt * 64 + scol1 * 8, &Vs[bufi][w * 1024 + 512]);
  };

  float m_run[2] = {-1e30f, -1e30f}, l_run[2] = {0.f, 0.f};
  f32x4 ao[2][4] = {};

  stage(0, 0);
  __syncthreads();

  int buf = 0;
  for (int kt = 0; kt < nt; ++kt) {
    if (kt + 1 < nt) stage(kt + 1, buf ^ 1);

    // padding mask: one ballot per tile; fast path when all 64 keys unmasked
    const unsigned long long bm = __ballot(amask[b * S_LEN + kt * 64 + lane] != 0);
    const bool allok = (bm == ~0ull);
    const bool diag = (kt >= nt - 2);

    // QK^T (swapped): sc[u][c] = K-chunk(16key x 32d) x Q(16q x 32d)
    f32x4 sc[2][4] = {};
#pragma unroll
    for (int c = 0; c < 4; ++c) {
      const int row = c * 16 + l15;
      const bf16s* kp = &Ks[buf][row * 64];
      const int xw = (row & 7) << 3;
      bf16x8 kb0 = *(const bf16x8*)(kp + ((lg * 8) ^ xw));
      bf16x8 kb1 = *(const bf16x8*)(kp + ((32 + lg * 8) ^ xw));
      sc[0][c] = __builtin_amdgcn_mfma_f32_16x16x32_bf16(kb0, aq[0][0], sc[0][c], 0, 0, 0);
      sc[0][c] = __builtin_amdgcn_mfma_f32_16x16x32_bf16(kb1, aq[0][1], sc[0][c], 0, 0, 0);
      sc[1][c] = __builtin_amdgcn_mfma_f32_16x16x32_bf16(kb0, aq[1][0], sc[1][c], 0, 0, 0);
      sc[1][c] = __builtin_amdgcn_mfma_f32_16x16x32_bf16(kb1, aq[1][1], sc[1][c], 0, 0, 0);
    }

    // online softmax per 16-row sub-block; lane owns q = l15 (keys = c*16+lg*4+r)
#pragma unroll
    for (int u = 0; u < 2; ++u) {
      const int qg = qt * 128 + w * 32 + u * 16 + l15;
      float mt = -1e30f;
#pragma unroll
      for (int c = 0; c < 4; ++c)
#pragma unroll
        for (int r = 0; r < 4; ++r) {
          float s = sc[u][c][r] * 0.125f;
          if (diag || !allok) {
            const int kg = kt * 64 + c * 16 + lg * 4 + r;
            if ((kg > qg) || (!allok && !((bm >> (kg & 63)) & 1))) s = -1e30f;
          }
          sc[u][c][r] = s;
          mt = fmaxf(mt, s);
        }
      mt = fmaxf(mt, __shfl_xor(mt, 16));
      mt = fmaxf(mt, __shfl_xor(mt, 32));
      const float mn = fmaxf(m_run[u], mt);
      const float al = __expf(m_run[u] - mn);
      m_run[u] = mn;
      float ls = 0.f;
#pragma unroll
      for (int c = 0; c < 4; ++c) {
        bf16x4 pk;
#pragma unroll
        for (int r = 0; r < 4; ++r) {
          const float p = __expf(sc[u][c][r] - mn);
          ls += p;
          pk[r] = f2bf(p);
        }
        const int prow = u * 16 + l15;
        *(bf16x4*)&Ps[w][prow * 64 + ((c * 16 + lg * 4) ^ ((prow & 7) << 3))] = pk;
      }
      ls += __shfl_xor(ls, 16);
      ls += __shfl_xor(ls, 32);
      l_run[u] = l_run[u] * al + ls;
#pragma unroll
      for (int vc = 0; vc < 4; ++vc)
#pragma unroll
        for (int r = 0; r < 4; ++r) ao[u][vc][r] *= al;
    }

    // P fragments (B-operand): lane holds P[q = l15][key = s*32 + lg*8 + j]
    bf16x8 pa[2][2];
#pragma unroll
    for (int u = 0; u < 2; ++u) {
      const int prow = u * 16 + l15;
      const int px = (prow & 7) << 3;
#pragma unroll
      for (int s = 0; s < 2; ++s)
        pa[u][s] = *(const bf16x8*)&Ps[w][prow * 64 + ((s * 32 + lg * 8) ^ px)];
    }

    // PV (swapped): ao[u][vc] += V^T-chunk(16d x 32key) x P(16q x 32key)
#pragma unroll
    for (int vc = 0; vc < 4; ++vc) {
      const int row = vc * 16 + l15;
      const bf16s* vp = &Vs[buf][row * 64];
      const int xw = (row & 7) << 3;
      bf16x8 vb0 = *(const bf16x8*)(vp + ((lg * 8) ^ xw));
      bf16x8 vb1 = *(const bf16x8*)(vp + ((32 + lg * 8) ^ xw));
      ao[0][vc] = __builtin_amdgcn_mfma_f32_16x16x32_bf16(vb0, pa[0][0], ao[0][vc], 0, 0, 0);
      ao[0][vc] = __builtin_amdgcn_mfma_f32_16x16x32_bf16(vb1, pa[0][1], ao[0][vc], 0, 0, 0);
      ao[1][vc] = __builtin_amdgcn_mfma_f32_16x16x32_bf16(vb0, pa[1][0], ao[1][vc], 0, 0, 0);
      ao[1][vc] = __builtin_amdgcn_mfma_f32_16x16x32_bf16(vb1, pa[1][1], ao[1][vc], 0, 0, 0);
    }

    __syncthreads();
    buf ^= 1;
  }

  // epilogue: lane owns q = l15; d = vc*16 + lg*4 + r -> bf16x4 stores
#pragma unroll
  for (int u = 0; u < 2; ++u) {
    const float inv = 1.0f / l_run[u];
    const size_t m = (size_t)b * S_LEN + qt * 128 + w * 32 + u * 16 + l15;
#pragma unroll
    for (int vc = 0; vc < 4; ++vc) {
      bf16x4 ov;
#pragma unroll
      for (int r = 0; r < 4; ++r) ov[r] = f2bf(ao[u][vc][r] * inv);
      *(bf16x4*)&out[m * KDIM + h * HDIM + vc * 16 + lg * 4] = ov;
    }
  }
}

// ---------------- launch ----------------
extern "C" void kernel_launch(void* const* d_in, const int* in_sizes, int n_in,
                              void* d_out, int out_size, void* d_ws, size_t ws_size,
                              hipStream_t stream) {
  const float* x  = (const float*)d_in[0];
  const int* pos  = (const int*)d_in[1];
  const int* am   = (const int*)d_in[2];
  const float* Wq = (const float*)d_in[3];
  const float* Wk = (const float*)d_in[4];
  const float* Wv = (const float*)d_in[5];
  const float* Wo = (const float*)d_in[6];
  float* out = (float*)d_out;

  char* ws = (char*)d_ws;
  const int M = BATCH * S_LEN;                 // 4096
  bf16s* xb  = (bf16s*)(ws);                   // 4096x2048
  bf16s* wqb = (bf16s*)(ws + 16777216);        // 2048x2048
  bf16s* wkb = (bf16s*)(ws + 25165824);        // 512x2048
  bf16s* wvb = (bf16s*)(ws + 27262976);        // 512x2048
  bf16s* wob = (bf16s*)(ws + 29360128);        // 2048x2048
  bf16s* qb  = (bf16s*)(ws + 37748736);        // 4096x2048
  bf16s* kb  = (bf16s*)(ws + 54525952);        // 4096x512
  bf16s* vtb = (bf16s*)(ws + 58720256);        // (2*8*64)x2048  (V^T)
  bf16s* aob = (bf16s*)(ws + 62914560);        // 4096x2048

  dim3 blk(256);
  auto cvt = [&](const float* s, bf16s* d, int n) {
    int g = (n / 8 + 255) / 256; if (g > 2048) g = 2048;
    k_cvt<<<dim3(g), blk, 0, stream>>>(s, d, n);
  };
  cvt(x,  xb,  M * KDIM);
  cvt(Wq, wqb, 2048 * 2048);
  cvt(Wk, wkb, 512 * 2048);
  cvt(Wv, wvb, 512 * 2048);
  cvt(Wo, wob, 2048 * 2048);

  k_gemm_bt<0><<<dim3(16, 32), blk, 0, stream>>>(xb, wqb, qb, M, 2048, 2048);
  k_gemm_bt<0><<<dim3(4, 32),  blk, 0, stream>>>(xb, wkb, kb, M, 512, 2048);
  k_gemm_bt<1><<<dim3(4, 32),  blk, 0, stream>>>(xb, wvb, vtb, M, 512, 2048);

  k_rope<<<dim3(1, M), blk, 0, stream>>>(qb, pos, 2048);
  k_rope<<<dim3(1, M), dim3(64), 0, stream>>>(kb, pos, 512);

  k_flash<<<dim3(BATCH * NH, S_LEN / 128), blk, 0, stream>>>(qb, kb, vtb, am, aob);

  k_gemm_bt<2><<<dim3(16, 32), blk, 0, stream>>>(aob, wob, out, M, 2048, 2048);
}